// Round 2
// baseline (6879.112 us; speedup 1.0000x reference)
//
#include <hip/hip_runtime.h>
#include <stdint.h>

#define IN_DIM    1024
#define OUT_DIM   1024
#define ROWSTRIDE 1025        // x has INPUT_DIM + CONDITION_DIM columns
#define BATCH     32768
#define NBASIS    6
#define KTOT      (NBASIS * IN_DIM)   // 6144

typedef __bf16 bf16x8 __attribute__((ext_vector_type(8)));
typedef float  f32x4  __attribute__((ext_vector_type(4)));

__device__ inline unsigned short f2bf(float f) {
  union { float f; unsigned u; } v; v.f = f;
  unsigned u = v.u;
  return (unsigned short)((u + 0x7FFFu + ((u >> 16) & 1u)) >> 16);  // RNE
}

// ---------- prep 1: feats fp32 -> bf16 [BATCH][1024], one block per row ----------
__global__ void prep_feats(const float* __restrict__ x, unsigned short* __restrict__ A) {
  int b = blockIdx.x;
  int tid = threadIdx.x;
  const float* xr = x + (size_t)b * ROWSTRIDE;
  unsigned short* ar = A + (size_t)b * IN_DIM;
  #pragma unroll
  for (int k = 0; k < 4; ++k) {
    int d = tid + k * 256;
    ar[d] = f2bf(xr[d]);
  }
}

// ---------- prep 2: weight [6144][1024] fp32 -> BT [1024][6144] bf16 ----------
__global__ void prep_wt(const float* __restrict__ w, unsigned short* __restrict__ bt) {
  __shared__ unsigned short t[32][33];
  int k0 = blockIdx.x * 32;   // over KTOT
  int e0 = blockIdx.y * 32;   // over OUT_DIM
  int tid = threadIdx.x;      // 256
  #pragma unroll
  for (int p = tid; p < 1024; p += 256) {
    int kk = p >> 5, ee = p & 31;                       // coalesced read over ee
    t[ee][kk] = f2bf(w[(size_t)(k0 + kk) * OUT_DIM + e0 + ee]);
  }
  __syncthreads();
  #pragma unroll
  for (int p = tid; p < 1024; p += 256) {
    int ee = p >> 5, kk = p & 31;                       // coalesced write over kk
    bt[(size_t)(e0 + ee) * KTOT + k0 + kk] = t[ee][kk];
  }
}

// ---------- GEMM ----------
__device__ inline void gload_lds16(const unsigned short* g, unsigned short* l) {
  __builtin_amdgcn_global_load_lds((const __attribute__((address_space(1))) void*)g,
                                   (__attribute__((address_space(3))) void*)l, 16, 0, 0);
}

__global__ __launch_bounds__(256, 3) void vcl_gemm(
    const unsigned short* __restrict__ A,    // [BATCH][1024] bf16 feats
    const unsigned short* __restrict__ BT,   // [1024][6144] bf16 W^T (n-major, k contiguous)
    const float* __restrict__ x,             // condition source
    const float* __restrict__ bias,
    float* __restrict__ out) {
  // 32 KB tile space; reused as the fp32 epilogue buffer afterwards.
  __shared__ unsigned short smem[2 * 128 * 64];
  __shared__ float basisT[NBASIS][128];
  unsigned short* sA = smem;
  unsigned short* sB = smem + 128 * 64;

  const int tid = threadIdx.x;
  const int bm0 = (blockIdx.x >> 3) * 128;
  const int bn0 = (blockIdx.x & 7) * 128;   // bn == XCD id (round-robin) -> B strip stays in its XCD L2

  if (tid < 128) {  // per-row basis table (transposed: basisT[c][row], f32x4-readable)
    float t = x[(size_t)(bm0 + tid) * ROWSTRIDE + IN_DIM];
    basisT[0][tid] = 1.0f;
    basisT[1][tid] = t;
    basisT[2][tid] = t * t;
    float r1 = fmaxf(t - 0.25f, 0.0f);
    float r2 = fmaxf(t - 0.50f, 0.0f);
    float r3 = fmaxf(t - 0.75f, 0.0f);
    basisT[3][tid] = r1 * r1;
    basisT[4][tid] = r2 * r2;
    basisT[5][tid] = r3 * r3;
  }

  const int wv   = tid >> 6;
  const int lane = tid & 63;
  const int lr   = lane >> 3;          // row within 8-row staging chunk
  const int kc   = (lane & 7) ^ lr;    // swizzled global k-chunk for this lane
  const int ln15 = lane & 15;
  const int quad = lane >> 4;
  const int wm   = wv >> 1, wn = wv & 1;
  const int cs0  = quad ^ (ln15 & 7);        // swizzled LDS slot, ks=0
  const int cs1  = (4 + quad) ^ (ln15 & 7);  // swizzled LDS slot, ks=1

  // staging address bases (lane-dependent)
  const unsigned short* gA[4];
  const unsigned short* gB[4];
  unsigned short* lA[4];
  unsigned short* lB[4];
  #pragma unroll
  for (int wc = 0; wc < 4; ++wc) {
    int r = wv * 32 + wc * 8 + lr;
    gA[wc] = A  + (size_t)(bm0 + r) * IN_DIM + kc * 8;
    gB[wc] = BT + (size_t)(bn0 + r) * KTOT   + kc * 8;
    lA[wc] = sA + (wv * 4 + wc) * 512;   // 1024 B per wave-instruction, lane*16 inside
    lB[wc] = sB + (wv * 4 + wc) * 512;
  }

  // bias for this thread's output columns (fixed for whole kernel)
  float bias_j[4];
  #pragma unroll
  for (int j = 0; j < 4; ++j)
    bias_j[j] = bias[bn0 + wn * 64 + j * 16 + ln15];

  f32x4 acc[4][4] = {};

  // initial stage: A(t=0) + B(t=0,c=0)
  #pragma unroll
  for (int wc = 0; wc < 4; ++wc) {
    gload_lds16(gA[wc], lA[wc]);
    gload_lds16(gB[wc], lB[wc]);
  }
  __syncthreads();   // staging done + basisT visible

  for (int t = 0; t < 16; ++t) {
    for (int c = 0; c < NBASIS; ++c) {
      // ---- compute this (t,c)'s partial into tmp, fold into acc ----
      bf16x8 bfr2[2][4];
      #pragma unroll
      for (int j = 0; j < 4; ++j) {
        int nt = wn * 64 + j * 16 + ln15;
        bfr2[0][j] = *(const bf16x8*)(sB + nt * 64 + cs0 * 8);
        bfr2[1][j] = *(const bf16x8*)(sB + nt * 64 + cs1 * 8);
      }

      f32x4 tmp[4][4];
      #pragma unroll
      for (int i = 0; i < 4; ++i) {
        int rowt = wm * 64 + i * 16 + ln15;
        bf16x8 af0 = *(const bf16x8*)(sA + rowt * 64 + cs0 * 8);
        bf16x8 af1 = *(const bf16x8*)(sA + rowt * 64 + cs1 * 8);
        #pragma unroll
        for (int j = 0; j < 4; ++j) {
          f32x4 z = {0.f, 0.f, 0.f, 0.f};
          z = __builtin_amdgcn_mfma_f32_16x16x32_bf16(af0, bfr2[0][j], z, 0, 0, 0);
          z = __builtin_amdgcn_mfma_f32_16x16x32_bf16(af1, bfr2[1][j], z, 0, 0, 0);
          tmp[i][j] = z;
        }
      }

      // ---- kick off next stage, then fold (VALU) under the load latency ----
      const bool last = (t == 15) && (c == NBASIS - 1);
      if (!last) {
        __syncthreads();   // all waves done reading sB (and sA at t-boundary)
        if (c < NBASIS - 1) {
          const int kB = c * IN_DIM + t * 64 + IN_DIM;   // B(t, c+1)
          #pragma unroll
          for (int wc = 0; wc < 4; ++wc)
            gload_lds16(gB[wc] + kB, lB[wc]);
        } else {
          const int kA = (t + 1) * 64;                   // A(t+1), B(t+1, 0)
          #pragma unroll
          for (int wc = 0; wc < 4; ++wc) {
            gload_lds16(gA[wc] + kA, lA[wc]);
            gload_lds16(gB[wc] + kA, lB[wc]);
          }
        }
      }

      // fold: acc[i][j] += basis[row, c] * tmp[i][j]  (elementwise f32x4 -> v_pk_fma_f32)
      #pragma unroll
      for (int i = 0; i < 4; ++i) {
        int rbase = wm * 64 + i * 16 + quad * 4;
        f32x4 bv = *(const f32x4*)&basisT[c][rbase];
        #pragma unroll
        for (int j = 0; j < 4; ++j)
          acc[i][j] += bv * tmp[i][j];
      }

      if (!last) __syncthreads();   // staged data visible for next (t,c)
    }
  }

  // ---- epilogue: reorganize via LDS for contiguous 512B row stores ----
  float* buf = (float*)smem;        // [32][132] fp32 = 16.5 KB, fits in the 32 KB tile space
  const int ROWP = 132;
  const int erow = tid >> 3;        // 0..31 compact row
  const int echk = tid & 7;         // 16-col chunk
  const int grow_base = bm0 + (erow >> 4) * 64 + (erow & 15);
  const int gcol = bn0 + echk * 16;

  #pragma unroll
  for (int i = 0; i < 4; ++i) {
    __syncthreads();   // protect buf reuse (and tile reads on first pass)
    #pragma unroll
    for (int j = 0; j < 4; ++j) {
      int cr = wm * 16 + quad * 4;                  // compact row base for this lane
      int cc = wn * 64 + j * 16 + ln15;
      #pragma unroll
      for (int r = 0; r < 4; ++r)
        buf[(cr + r) * ROWP + cc] = acc[i][j][r] + bias_j[j];
    }
    __syncthreads();
    float* orow = out + (size_t)(grow_base + i * 16) * OUT_DIM + gcol;
    const float* brow = buf + erow * ROWP + echk * 16;
    #pragma unroll
    for (int e = 0; e < 4; ++e)
      *(f32x4*)(orow + e * 4) = *(const f32x4*)(brow + e * 4);
  }
}

extern "C" void kernel_launch(void* const* d_in, const int* in_sizes, int n_in,
                              void* d_out, int out_size, void* d_ws, size_t ws_size,
                              hipStream_t stream) {
  const float* x    = (const float*)d_in[0];
  const float* w    = (const float*)d_in[1];
  const float* bias = (const float*)d_in[2];
  float* out = (float*)d_out;

  // ws layout: A' bf16 [32768][1024] = 64 MiB, then BT bf16 [1024][6144] = 12 MiB
  unsigned short* A  = (unsigned short*)d_ws;
  unsigned short* BT = (unsigned short*)((char*)d_ws + (size_t)BATCH * IN_DIM * 2);

  prep_feats<<<BATCH, 256, 0, stream>>>(x, A);
  dim3 g2(KTOT / 32, OUT_DIM / 32);
  prep_wt<<<g2, 256, 0, stream>>>(w, BT);
  vcl_gemm<<<(BATCH / 128) * (OUT_DIM / 128), 256, 0, stream>>>(A, BT, x, bias, out);
}

// Round 3
// 772.688 us; speedup vs baseline: 8.9028x; 8.9028x over previous
//
#include <hip/hip_runtime.h>
#include <stdint.h>

#define IN_DIM    1024
#define OUT_DIM   1024
#define ROWSTRIDE 1025        // x has INPUT_DIM + CONDITION_DIM columns
#define BATCH     32768
#define NBASIS    6
#define KTOT      (NBASIS * IN_DIM)   // 6144
#define KSTEPS    (KTOT / 64)         // 96

typedef __bf16 bf16x8 __attribute__((ext_vector_type(8)));
typedef float  f32x4  __attribute__((ext_vector_type(4)));

__device__ inline unsigned short f2bf(float f) {
  union { float f; unsigned u; } v; v.f = f;
  unsigned u = v.u;
  return (unsigned short)((u + 0x7FFFu + ((u >> 16) & 1u)) >> 16);  // RNE
}

// ---------- prep 1: expand feats -> A'[b][c*1024+d] = bf16(basis[b,c]*feats[b,d]) ----------
__global__ void prep_feats(const float* __restrict__ x, unsigned short* __restrict__ A2) {
  const int b = blockIdx.x;
  const int tid = threadIdx.x;            // 256
  const float* xr = x + (size_t)b * ROWSTRIDE;
  const float t = xr[IN_DIM];
  float bas[NBASIS];
  bas[0] = 1.0f; bas[1] = t; bas[2] = t * t;
  float r1 = fmaxf(t - 0.25f, 0.0f);
  float r2 = fmaxf(t - 0.50f, 0.0f);
  float r3 = fmaxf(t - 0.75f, 0.0f);
  bas[3] = r1 * r1; bas[4] = r2 * r2; bas[5] = r3 * r3;

  unsigned short* arow = A2 + (size_t)b * KTOT;
  #pragma unroll
  for (int k = 0; k < 2; ++k) {
    int d = k * 512 + tid * 2;
    float v0 = xr[d], v1 = xr[d + 1];
    #pragma unroll
    for (int c = 0; c < NBASIS; ++c) {
      union { unsigned short u[2]; unsigned int w; } p;
      p.u[0] = f2bf(bas[c] * v0);
      p.u[1] = f2bf(bas[c] * v1);
      *(unsigned int*)(arow + c * IN_DIM + d) = p.w;   // 4B-aligned coalesced store
    }
  }
}

// ---------- prep 2: weight [6144][1024] fp32 -> BT [1024][6144] bf16 ----------
__global__ void prep_wt(const float* __restrict__ w, unsigned short* __restrict__ bt) {
  __shared__ unsigned short t[32][33];
  int k0 = blockIdx.x * 32;   // over KTOT
  int e0 = blockIdx.y * 32;   // over OUT_DIM
  int tid = threadIdx.x;      // 256
  #pragma unroll
  for (int p = tid; p < 1024; p += 256) {
    int kk = p >> 5, ee = p & 31;                       // coalesced read over ee
    t[ee][kk] = f2bf(w[(size_t)(k0 + kk) * OUT_DIM + e0 + ee]);
  }
  __syncthreads();
  #pragma unroll
  for (int p = tid; p < 1024; p += 256) {
    int ee = p >> 5, kk = p & 31;                       // coalesced write over kk
    bt[(size_t)(e0 + ee) * KTOT + k0 + kk] = t[ee][kk];
  }
}

// ---------- pure bf16 GEMM: out[b][e] = sum_k A'[b][k] * BT[e][k] + bias[e] ----------
__device__ inline void gload_lds16(const unsigned short* g, unsigned short* l) {
  __builtin_amdgcn_global_load_lds((const __attribute__((address_space(1))) void*)g,
                                   (__attribute__((address_space(3))) void*)l, 16, 0, 0);
}

__global__ __launch_bounds__(256, 3) void vcl_gemm(
    const unsigned short* __restrict__ A2,   // [BATCH][KTOT] bf16 (basis-scaled)
    const unsigned short* __restrict__ BT,   // [OUT_DIM][KTOT] bf16 W^T (k contiguous)
    const float* __restrict__ bias,
    float* __restrict__ out) {
  // 32 KB tile space; reused as the fp32 epilogue buffer afterwards.
  __shared__ unsigned short smem[2 * 128 * 64];
  unsigned short* sA = smem;
  unsigned short* sB = smem + 128 * 64;

  const int tid = threadIdx.x;
  const int bm0 = (blockIdx.x >> 3) * 128;
  const int bn0 = (blockIdx.x & 7) * 128;   // bn == XCD id (round-robin) -> B strip L2-resident

  const int wv   = tid >> 6;
  const int lane = tid & 63;
  const int lr   = lane >> 3;          // row within 8-row staging chunk
  const int kc   = (lane & 7) ^ lr;    // swizzled global k-chunk for this lane
  const int ln15 = lane & 15;
  const int quad = lane >> 4;
  const int wm   = wv >> 1, wn = wv & 1;
  const int cs0  = quad ^ (ln15 & 7);        // swizzled LDS slot, ks=0
  const int cs1  = (4 + quad) ^ (ln15 & 7);  // swizzled LDS slot, ks=1

  // staging address bases (lane-dependent)
  const unsigned short* gA[4];
  const unsigned short* gB[4];
  unsigned short* lA[4];
  unsigned short* lB[4];
  #pragma unroll
  for (int wc = 0; wc < 4; ++wc) {
    int r = wv * 32 + wc * 8 + lr;
    gA[wc] = A2 + (size_t)(bm0 + r) * KTOT + kc * 8;
    gB[wc] = BT + (size_t)(bn0 + r) * KTOT + kc * 8;
    lA[wc] = sA + (wv * 4 + wc) * 512;   // 1024 B per wave-instruction, lane*16 inside
    lB[wc] = sB + (wv * 4 + wc) * 512;
  }

  // bias for this thread's output columns
  float bias_j[4];
  #pragma unroll
  for (int j = 0; j < 4; ++j)
    bias_j[j] = bias[bn0 + wn * 64 + j * 16 + ln15];

  f32x4 acc[4][4] = {};

  // stage k-step 0
  #pragma unroll
  for (int wc = 0; wc < 4; ++wc) {
    gload_lds16(gA[wc], lA[wc]);
    gload_lds16(gB[wc], lB[wc]);
  }

  for (int t = 0; t < KSTEPS; ++t) {
    __syncthreads();   // staged tile visible (drains vmcnt)

    bf16x8 bfr2[2][4];
    #pragma unroll
    for (int j = 0; j < 4; ++j) {
      int nt = wn * 64 + j * 16 + ln15;
      bfr2[0][j] = *(const bf16x8*)(sB + nt * 64 + cs0 * 8);
      bfr2[1][j] = *(const bf16x8*)(sB + nt * 64 + cs1 * 8);
    }
    #pragma unroll
    for (int i = 0; i < 4; ++i) {
      int rowt = wm * 64 + i * 16 + ln15;
      bf16x8 af0 = *(const bf16x8*)(sA + rowt * 64 + cs0 * 8);
      bf16x8 af1 = *(const bf16x8*)(sA + rowt * 64 + cs1 * 8);
      #pragma unroll
      for (int j = 0; j < 4; ++j) {
        acc[i][j] = __builtin_amdgcn_mfma_f32_16x16x32_bf16(af0, bfr2[0][j], acc[i][j], 0, 0, 0);
        acc[i][j] = __builtin_amdgcn_mfma_f32_16x16x32_bf16(af1, bfr2[1][j], acc[i][j], 0, 0, 0);
      }
    }

    __syncthreads();   // all waves done reading tile t
    if (t + 1 < KSTEPS) {
      const int kOff = (t + 1) * 64;
      #pragma unroll
      for (int wc = 0; wc < 4; ++wc) {
        gload_lds16(gA[wc] + kOff, lA[wc]);
        gload_lds16(gB[wc] + kOff, lB[wc]);
      }
    }
  }

  // ---- epilogue: reorganize via LDS for contiguous 512B row stores ----
  float* buf = (float*)smem;        // [32][132] fp32 = 16.9 KB, fits in 32 KB tile space
  const int ROWP = 132;
  const int erow = tid >> 3;        // 0..31 compact row
  const int echk = tid & 7;         // 16-col chunk
  const int grow_base = bm0 + (erow >> 4) * 64 + (erow & 15);
  const int gcol = bn0 + echk * 16;

  #pragma unroll
  for (int i = 0; i < 4; ++i) {
    __syncthreads();   // protect buf reuse (and tile reads on first pass)
    #pragma unroll
    for (int j = 0; j < 4; ++j) {
      int cr = wm * 16 + quad * 4;                  // compact row base for this lane
      int cc = wn * 64 + j * 16 + ln15;
      #pragma unroll
      for (int r = 0; r < 4; ++r)
        buf[(cr + r) * ROWP + cc] = acc[i][j][r] + bias_j[j];
    }
    __syncthreads();
    float* orow = out + (size_t)(grow_base + i * 16) * OUT_DIM + gcol;
    const float* brow = buf + erow * ROWP + echk * 16;
    #pragma unroll
    for (int e = 0; e < 4; ++e)
      *(f32x4*)(orow + e * 4) = *(const f32x4*)(brow + e * 4);
  }
}

extern "C" void kernel_launch(void* const* d_in, const int* in_sizes, int n_in,
                              void* d_out, int out_size, void* d_ws, size_t ws_size,
                              hipStream_t stream) {
  const float* x    = (const float*)d_in[0];
  const float* w    = (const float*)d_in[1];
  const float* bias = (const float*)d_in[2];
  float* out = (float*)d_out;

  // ws layout: A' bf16 [32768][6144] = 384 MiB, then BT bf16 [1024][6144] = 12 MiB
  unsigned short* A2 = (unsigned short*)d_ws;
  unsigned short* BT = (unsigned short*)((char*)d_ws + (size_t)BATCH * KTOT * 2);

  prep_feats<<<BATCH, 256, 0, stream>>>(x, A2);
  dim3 g2(KTOT / 32, OUT_DIM / 32);
  prep_wt<<<g2, 256, 0, stream>>>(w, BT);
  vcl_gemm<<<(BATCH / 128) * (OUT_DIM / 128), 256, 0, stream>>>(A2, BT, bias, out);
}